// Round 2
// baseline (545.381 us; speedup 1.0000x reference)
//
#include <hip/hip_runtime.h>
#include <hip/hip_bf16.h>

#define NRES 256
#define CH   128
#define NH   4
#define HD   32
#define NPX  (NRES*NRES)   // 65536 pixels

typedef __hip_bfloat16 bf16;

__device__ __forceinline__ float b2f(bf16 x) { return __bfloat162float(x); }
__device__ __forceinline__ float lo_f(unsigned u) { return __uint_as_float(u << 16); }
__device__ __forceinline__ float hi_f(unsigned u) { return __uint_as_float(u & 0xffff0000u); }

// ---------------- Kernel 1: LN + projections q,k,v,g + pair bias ----------------
// block = 256 threads, 32 pixels per block; all-f32 inputs, bf16 intermediate outputs
__global__ __launch_bounds__(256) void proj_kernel(const float* __restrict__ x2d,
                                                   const float* __restrict__ nw,
                                                   const float* __restrict__ nb,
                                                   const float* __restrict__ wq,
                                                   const float* __restrict__ wk,
                                                   const float* __restrict__ wv,
                                                   const float* __restrict__ wg,
                                                   const float* __restrict__ bg,
                                                   const float* __restrict__ wb,
                                                   bf16* __restrict__ q,
                                                   bf16* __restrict__ k,
                                                   bf16* __restrict__ v,
                                                   bf16* __restrict__ g,
                                                   float* __restrict__ bias) {
    __shared__ float xs[32][CH];   // 16 KB
    int t = threadIdx.x;
    size_t pbase = (size_t)blockIdx.x * 32;

    // load raw x2d block (f32)
    for (int l = 0; l < 16; ++l) {
        int f = t + 256 * l;
        xs[f >> 7][f & 127] = x2d[pbase * CH + f];
    }
    __syncthreads();

    // LayerNorm in-place: 8 threads per pixel, each handles 16 channels (stride 8)
    {
        int px = t >> 3, lo = t & 7;
        float s = 0.f, ss = 0.f;
        #pragma unroll
        for (int cc = 0; cc < 16; ++cc) {
            float x = xs[px][lo + 8 * cc];
            s += x; ss += x * x;
        }
        s += __shfl_xor(s, 1); ss += __shfl_xor(ss, 1);
        s += __shfl_xor(s, 2); ss += __shfl_xor(ss, 2);
        s += __shfl_xor(s, 4); ss += __shfl_xor(ss, 4);
        float mu  = s * (1.0f / CH);
        float var = ss * (1.0f / CH) - mu * mu;
        float rs  = rsqrtf(var + 1e-5f);
        #pragma unroll
        for (int cc = 0; cc < 16; ++cc) {
            int c = lo + 8 * cc;
            xs[px][c] = (xs[px][c] - mu) * rs * nw[c] + nb[c];
        }
    }
    __syncthreads();

    int o   = t & 127;
    int px0 = t >> 7;   // 0 or 1
    const float* Ws[4] = {wq, wk, wv, wg};
    bf16*        Os[4] = {q, k, v, g};
    const float qscale = 0.17677669529663689f;   // 1/sqrt(32)

    #pragma unroll
    for (int mat = 0; mat < 4; ++mat) {
        const float* W = Ws[mat] + (size_t)o * CH;
        float acc[16];
        #pragma unroll
        for (int i = 0; i < 16; ++i) acc[i] = 0.f;
        for (int c0 = 0; c0 < CH; c0 += 4) {
            float4 w4 = *reinterpret_cast<const float4*>(W + c0);
            #pragma unroll
            for (int i = 0; i < 16; ++i) {
                int px = px0 + 2 * i;
                acc[i] += xs[px][c0] * w4.x + xs[px][c0 + 1] * w4.y
                        + xs[px][c0 + 2] * w4.z + xs[px][c0 + 3] * w4.w;
            }
        }
        #pragma unroll
        for (int i = 0; i < 16; ++i) {
            int px = px0 + 2 * i;
            float r = acc[i];
            if (mat == 0) r *= qscale;
            if (mat == 3) r = 1.f / (1.f + __expf(-(r + bg[o])));
            Os[mat][(pbase + px) * CH + o] = __float2bfloat16(r);
        }
    }

    // pair bias: bias[h, i, j] = sum_c xn[i,j,c] * wb[h,c]; pixel p == i*256+j
    if (t < 128) {
        int px = t >> 2, h = t & 3;
        float a = 0.f;
        for (int c = 0; c < CH; ++c) a += xs[px][c] * wb[h * CH + c];
        bias[(size_t)h * NPX + pbase + px] = a;
    }
}

// ---------------- Kernel 2: per-(row m, head h) attention + gating ----------------
// block = 256 threads (one per query i); K,V for (m,h) staged in LDS (f32)
__global__ __launch_bounds__(256) void attn_kernel(const bf16* q,
                                                   const bf16* __restrict__ kk,
                                                   const bf16* __restrict__ vv,
                                                   const float* __restrict__ bias,
                                                   const bf16* __restrict__ gg,
                                                   bf16* attn) {
    __shared__ float ks[NRES][HD];   // 32 KB
    __shared__ float vs[NRES][HD];   // 32 KB
    int m = blockIdx.x;
    int h = blockIdx.y;
    int t = threadIdx.x;
    size_t base = ((size_t)m * NRES) * CH + (size_t)h * HD;

    // stage K,V: each thread loads 8 consecutive bf16 per iter
    for (int l = 0; l < 4; ++l) {
        int e = (l * 256 + t) * 8;       // 0..8191, step 8
        int j = e >> 5, d = e & 31;
        uint4 ku = *reinterpret_cast<const uint4*>(kk + base + (size_t)j * CH + d);
        uint4 vu = *reinterpret_cast<const uint4*>(vv + base + (size_t)j * CH + d);
        ks[j][d + 0] = lo_f(ku.x); ks[j][d + 1] = hi_f(ku.x);
        ks[j][d + 2] = lo_f(ku.y); ks[j][d + 3] = hi_f(ku.y);
        ks[j][d + 4] = lo_f(ku.z); ks[j][d + 5] = hi_f(ku.z);
        ks[j][d + 6] = lo_f(ku.w); ks[j][d + 7] = hi_f(ku.w);
        vs[j][d + 0] = lo_f(vu.x); vs[j][d + 1] = hi_f(vu.x);
        vs[j][d + 2] = lo_f(vu.y); vs[j][d + 3] = hi_f(vu.y);
        vs[j][d + 4] = lo_f(vu.z); vs[j][d + 5] = hi_f(vu.z);
        vs[j][d + 6] = lo_f(vu.w); vs[j][d + 7] = hi_f(vu.w);
    }
    __syncthreads();

    int i = t;
    // load q row (bf16, pre-scaled by 1/sqrt(D)) into registers
    float qr[HD];
    {
        const uint4* qp = reinterpret_cast<const uint4*>(q + base + (size_t)i * CH);
        #pragma unroll
        for (int c = 0; c < 4; ++c) {
            uint4 u = qp[c];
            qr[c * 8 + 0] = lo_f(u.x); qr[c * 8 + 1] = hi_f(u.x);
            qr[c * 8 + 2] = lo_f(u.y); qr[c * 8 + 3] = hi_f(u.y);
            qr[c * 8 + 4] = lo_f(u.z); qr[c * 8 + 5] = hi_f(u.z);
            qr[c * 8 + 6] = lo_f(u.w); qr[c * 8 + 7] = hi_f(u.w);
        }
    }
    const float* brow = bias + (size_t)h * NPX + (size_t)i * NRES;

    float mrun = -1e30f, lsum = 0.f;
    float o[HD];
    #pragma unroll
    for (int d = 0; d < HD; ++d) o[d] = 0.f;

    for (int j = 0; j < NRES; ++j) {
        float s0 = brow[j], s1 = 0.f, s2 = 0.f, s3 = 0.f;
        #pragma unroll
        for (int d = 0; d < HD; d += 4) {
            s0 += qr[d + 0] * ks[j][d + 0];
            s1 += qr[d + 1] * ks[j][d + 1];
            s2 += qr[d + 2] * ks[j][d + 2];
            s3 += qr[d + 3] * ks[j][d + 3];
        }
        float s = (s0 + s1) + (s2 + s3);
        if (s > mrun) {
            float r = __expf(mrun - s);
            lsum *= r;
            #pragma unroll
            for (int d = 0; d < HD; ++d) o[d] *= r;
            mrun = s;
        }
        float pj = __expf(s - mrun);
        lsum += pj;
        #pragma unroll
        for (int d = 0; d < HD; ++d) o[d] += pj * vs[j][d];
    }

    // normalize, gate, store (in-place over q buffer; disjoint per-(m,h) slices)
    float inv = 1.f / lsum;
    float gd[HD];
    {
        const uint4* gp = reinterpret_cast<const uint4*>(gg + base + (size_t)i * CH);
        #pragma unroll
        for (int c = 0; c < 4; ++c) {
            uint4 u = gp[c];
            gd[c * 8 + 0] = lo_f(u.x); gd[c * 8 + 1] = hi_f(u.x);
            gd[c * 8 + 2] = lo_f(u.y); gd[c * 8 + 3] = hi_f(u.y);
            gd[c * 8 + 4] = lo_f(u.z); gd[c * 8 + 5] = hi_f(u.z);
            gd[c * 8 + 6] = lo_f(u.w); gd[c * 8 + 7] = hi_f(u.w);
        }
    }
    #pragma unroll
    for (int d = 0; d < HD; ++d)
        attn[base + (size_t)i * CH + d] = __float2bfloat16(o[d] * inv * gd[d]);
}

// ---------------- Kernel 3: output projection (f32 out) ----------------
__global__ __launch_bounds__(256) void out_kernel(const bf16* __restrict__ ga,
                                                  const float* __restrict__ wo,
                                                  const float* __restrict__ bo,
                                                  float* __restrict__ out) {
    __shared__ float xs[32][CH];
    int t = threadIdx.x;
    size_t pbase = (size_t)blockIdx.x * 32;

    for (int l = 0; l < 2; ++l) {
        int e = (l * 256 + t) * 8;   // 0..4095, step 8
        uint4 u = *reinterpret_cast<const uint4*>(ga + pbase * CH + e);
        int px = e >> 7, c = e & 127;
        xs[px][c + 0] = lo_f(u.x); xs[px][c + 1] = hi_f(u.x);
        xs[px][c + 2] = lo_f(u.y); xs[px][c + 3] = hi_f(u.y);
        xs[px][c + 4] = lo_f(u.z); xs[px][c + 5] = hi_f(u.z);
        xs[px][c + 6] = lo_f(u.w); xs[px][c + 7] = hi_f(u.w);
    }
    __syncthreads();

    int o   = t & 127;
    int px0 = t >> 7;
    const float* W = wo + (size_t)o * CH;
    float acc[16];
    #pragma unroll
    for (int i = 0; i < 16; ++i) acc[i] = 0.f;
    for (int c0 = 0; c0 < CH; c0 += 4) {
        float4 w4 = *reinterpret_cast<const float4*>(W + c0);
        #pragma unroll
        for (int i = 0; i < 16; ++i) {
            int px = px0 + 2 * i;
            acc[i] += xs[px][c0] * w4.x + xs[px][c0 + 1] * w4.y
                    + xs[px][c0 + 2] * w4.z + xs[px][c0 + 3] * w4.w;
        }
    }
    float bov = bo[o];
    #pragma unroll
    for (int i = 0; i < 16; ++i) {
        int px = px0 + 2 * i;
        out[(pbase + px) * CH + o] = acc[i] + bov;
    }
}

extern "C" void kernel_launch(void* const* d_in, const int* in_sizes, int n_in,
                              void* d_out, int out_size, void* d_ws, size_t ws_size,
                              hipStream_t stream) {
    const float* x2d = (const float*)d_in[0];
    const float* nw  = (const float*)d_in[1];
    const float* nb  = (const float*)d_in[2];
    const float* wq  = (const float*)d_in[3];
    const float* wk  = (const float*)d_in[4];
    const float* wv  = (const float*)d_in[5];
    const float* wb  = (const float*)d_in[6];
    const float* wg  = (const float*)d_in[7];
    const float* bg  = (const float*)d_in[8];
    const float* wo  = (const float*)d_in[9];
    const float* bo  = (const float*)d_in[10];
    float* out = (float*)d_out;

    // workspace: bias (f32, 1 MB) then q,k,v,g (bf16, 16.8 MB each) = 68 MB total
    float* bias = (float*)d_ws;
    bf16*  q    = (bf16*)((float*)d_ws + (size_t)NH * NPX);
    bf16*  k    = q + (size_t)NPX * CH;
    bf16*  v    = k + (size_t)NPX * CH;
    bf16*  g    = v + (size_t)NPX * CH;

    proj_kernel<<<NPX / 32, 256, 0, stream>>>(x2d, nw, nb, wq, wk, wv, wg, bg, wb,
                                              q, k, v, g, bias);
    attn_kernel<<<dim3(NRES, NH), 256, 0, stream>>>(q, k, v, bias, g, q);
    out_kernel<<<NPX / 32, 256, 0, stream>>>(q, wo, bo, out);
}

// Round 3
// 344.731 us; speedup vs baseline: 1.5821x; 1.5821x over previous
//
#include <hip/hip_runtime.h>
#include <hip/hip_bf16.h>

#define NRES 256
#define CH   128
#define NH   4
#define HD   32
#define NPX  (NRES*NRES)   // 65536 pixels

typedef __hip_bfloat16 bf16;
typedef __attribute__((ext_vector_type(8))) short bf16x8;
typedef __attribute__((ext_vector_type(4))) float f32x4;

__device__ __forceinline__ float b2f(bf16 x) { return __bfloat162float(x); }
__device__ __forceinline__ float lo_f(unsigned u) { return __uint_as_float(u << 16); }
__device__ __forceinline__ float hi_f(unsigned u) { return __uint_as_float(u & 0xffff0000u); }
__device__ __forceinline__ unsigned pk2(float a, float b) {
    unsigned short ua = __bfloat16_as_ushort(__float2bfloat16(a));
    unsigned short ub = __bfloat16_as_ushort(__float2bfloat16(b));
    return (unsigned)ua | ((unsigned)ub << 16);
}

// ---------------- Kernel 1: LN + projections q,k,v,g + pair bias ----------------
__global__ __launch_bounds__(256) void proj_kernel(const float* __restrict__ x2d,
                                                   const float* __restrict__ nw,
                                                   const float* __restrict__ nb,
                                                   const float* __restrict__ wq,
                                                   const float* __restrict__ wk,
                                                   const float* __restrict__ wv,
                                                   const float* __restrict__ wg,
                                                   const float* __restrict__ bg,
                                                   const float* __restrict__ wb,
                                                   bf16* __restrict__ q,
                                                   bf16* __restrict__ k,
                                                   bf16* __restrict__ v,
                                                   bf16* __restrict__ g,
                                                   float* __restrict__ bias) {
    __shared__ float xs[32][CH];   // 16 KB
    int t = threadIdx.x;
    size_t pbase = (size_t)blockIdx.x * 32;

    for (int l = 0; l < 16; ++l) {
        int f = t + 256 * l;
        xs[f >> 7][f & 127] = x2d[pbase * CH + f];
    }
    __syncthreads();

    {
        int px = t >> 3, lo = t & 7;
        float s = 0.f, ss = 0.f;
        #pragma unroll
        for (int cc = 0; cc < 16; ++cc) {
            float x = xs[px][lo + 8 * cc];
            s += x; ss += x * x;
        }
        s += __shfl_xor(s, 1); ss += __shfl_xor(ss, 1);
        s += __shfl_xor(s, 2); ss += __shfl_xor(ss, 2);
        s += __shfl_xor(s, 4); ss += __shfl_xor(ss, 4);
        float mu  = s * (1.0f / CH);
        float var = ss * (1.0f / CH) - mu * mu;
        float rs  = rsqrtf(var + 1e-5f);
        #pragma unroll
        for (int cc = 0; cc < 16; ++cc) {
            int c = lo + 8 * cc;
            xs[px][c] = (xs[px][c] - mu) * rs * nw[c] + nb[c];
        }
    }
    __syncthreads();

    int o   = t & 127;
    int px0 = t >> 7;
    const float* Ws[4] = {wq, wk, wv, wg};
    bf16*        Os[4] = {q, k, v, g};
    const float qscale = 0.17677669529663689f;   // 1/sqrt(32)

    #pragma unroll
    for (int mat = 0; mat < 4; ++mat) {
        const float* W = Ws[mat] + (size_t)o * CH;
        float acc[16];
        #pragma unroll
        for (int i = 0; i < 16; ++i) acc[i] = 0.f;
        for (int c0 = 0; c0 < CH; c0 += 4) {
            float4 w4 = *reinterpret_cast<const float4*>(W + c0);
            #pragma unroll
            for (int i = 0; i < 16; ++i) {
                int px = px0 + 2 * i;
                acc[i] += xs[px][c0] * w4.x + xs[px][c0 + 1] * w4.y
                        + xs[px][c0 + 2] * w4.z + xs[px][c0 + 3] * w4.w;
            }
        }
        #pragma unroll
        for (int i = 0; i < 16; ++i) {
            int px = px0 + 2 * i;
            float r = acc[i];
            if (mat == 0) r *= qscale;
            if (mat == 3) r = 1.f / (1.f + __expf(-(r + bg[o])));
            Os[mat][(pbase + px) * CH + o] = __float2bfloat16(r);
        }
    }

    if (t < 128) {
        int px = t >> 2, h = t & 3;
        float a = 0.f;
        for (int c = 0; c < CH; ++c) a += xs[px][c] * wb[h * CH + c];
        bias[(size_t)h * NPX + pbase + px] = a;
    }
}

// ---------------- Kernel 2: MFMA flash attention per (m,h) ----------------
// 4 waves x 64 query rows; S^T = mfma(K, Q); O^T = mfma(V^T, P^T)
__global__ __launch_bounds__(256) void attn_kernel(const bf16* q,
                                                   const bf16* __restrict__ kk,
                                                   const bf16* __restrict__ vv,
                                                   const float* __restrict__ bias,
                                                   const bf16* __restrict__ gg,
                                                   bf16* attn) {
    __shared__ short kl[NRES][HD];        // 16 KB, swizzled d-blocks
    __shared__ short vt[HD][NRES];        // 16 KB, transposed, swizzled j-blocks
    __shared__ short pl[4][64][64];       // 32 KB, per-wave P^T tile (as P[i][j])

    int t  = threadIdx.x;
    int w  = t >> 6;
    int l  = t & 63;
    int lg = l >> 4;       // lane group 0..3
    int ll = l & 15;       // lane low 0..15
    int m = blockIdx.x, h = blockIdx.y;
    size_t base = ((size_t)m * NRES) * CH + (size_t)h * HD;

    // ---- stage K (swizzled) and V (transposed+swizzled) ----
    for (int it = 0; it < 4; ++it) {
        int e8 = t + 256 * it;            // 0..1023 -> 8 elems each
        int j  = e8 >> 2;
        int d0 = (e8 & 3) * 8;
        uint4 ku = *reinterpret_cast<const uint4*>(kk + base + (size_t)j * CH + d0);
        *reinterpret_cast<uint4*>(&kl[j][d0 ^ (8 * ((j >> 1) & 3))]) = ku;
        uint4 vu = *reinterpret_cast<const uint4*>(vv + base + (size_t)j * CH + d0);
        union { uint4 u; short s[8]; } vc; vc.u = vu;
        #pragma unroll
        for (int s = 0; s < 8; ++s)
            vt[d0 + s][j ^ (8 * s)] = vc.s[s];
    }

    // ---- Q fragments (B-operand): i = w*64 + 16n + ll, d = 8*lg..+7 ----
    bf16x8 qf[4];
    #pragma unroll
    for (int n = 0; n < 4; ++n)
        qf[n] = *reinterpret_cast<const bf16x8*>(q + base + (size_t)(w * 64 + 16 * n + ll) * CH + 8 * lg);

    __syncthreads();

    float m_run[4], l_run[4];
    f32x4 oacc[2][4];
    #pragma unroll
    for (int n = 0; n < 4; ++n) { m_run[n] = -1e30f; l_run[n] = 0.f; }
    #pragma unroll
    for (int dm = 0; dm < 2; ++dm)
        #pragma unroll
        for (int n = 0; n < 4; ++n) oacc[dm][n] = (f32x4){0.f, 0.f, 0.f, 0.f};

    for (int jt = 0; jt < 4; ++jt) {
        // ---- S^T tile: rows j (64), cols i (64) ----
        f32x4 sacc[4][4];
        #pragma unroll
        for (int mj = 0; mj < 4; ++mj)
            #pragma unroll
            for (int n = 0; n < 4; ++n) sacc[mj][n] = (f32x4){0.f, 0.f, 0.f, 0.f};

        #pragma unroll
        for (int mj = 0; mj < 4; ++mj) {
            int jrow = jt * 64 + 16 * mj + ll;
            bf16x8 kf = *reinterpret_cast<const bf16x8*>(&kl[jrow][(8 * lg) ^ (8 * ((jrow >> 1) & 3))]);
            #pragma unroll
            for (int n = 0; n < 4; ++n)
                sacc[mj][n] = __builtin_amdgcn_mfma_f32_16x16x32_bf16(kf, qf[n], sacc[mj][n], 0, 0, 0);
        }

        // ---- add bias[h][i][j] (float4 over r-consecutive j) ----
        #pragma unroll
        for (int n = 0; n < 4; ++n) {
            int i = w * 64 + 16 * n + ll;
            #pragma unroll
            for (int mj = 0; mj < 4; ++mj) {
                float4 b4 = *reinterpret_cast<const float4*>(bias + (size_t)h * NPX + (size_t)i * NRES + jt * 64 + 16 * mj + 4 * lg);
                sacc[mj][n][0] += b4.x; sacc[mj][n][1] += b4.y;
                sacc[mj][n][2] += b4.z; sacc[mj][n][3] += b4.w;
            }
        }

        // ---- online softmax per i (column of S^T) + pack P to LDS ----
        #pragma unroll
        for (int n = 0; n < 4; ++n) {
            float mx = -1e30f;
            #pragma unroll
            for (int mj = 0; mj < 4; ++mj)
                #pragma unroll
                for (int r = 0; r < 4; ++r) mx = fmaxf(mx, sacc[mj][n][r]);
            mx = fmaxf(mx, __shfl_xor(mx, 16));
            mx = fmaxf(mx, __shfl_xor(mx, 32));
            float mnew  = fmaxf(m_run[n], mx);
            float scale = __expf(m_run[n] - mnew);
            l_run[n] *= scale;
            #pragma unroll
            for (int dm = 0; dm < 2; ++dm)
                #pragma unroll
                for (int r = 0; r < 4; ++r) oacc[dm][n][r] *= scale;
            m_run[n] = mnew;

            float psum = 0.f;
            #pragma unroll
            for (int mj = 0; mj < 4; ++mj) {
                #pragma unroll
                for (int r = 0; r < 4; ++r) {
                    float p = __expf(sacc[mj][n][r] - mnew);
                    sacc[mj][n][r] = p;
                    psum += p;
                }
            }
            psum += __shfl_xor(psum, 16);
            psum += __shfl_xor(psum, 32);
            l_run[n] += psum;

            int iloc = 16 * n + ll;
            #pragma unroll
            for (int mj = 0; mj < 4; ++mj) {
                int jb = (16 * mj + 4 * lg) ^ (8 * (iloc & 7));
                uint2 pw;
                pw.x = pk2(sacc[mj][n][0], sacc[mj][n][1]);
                pw.y = pk2(sacc[mj][n][2], sacc[mj][n][3]);
                *reinterpret_cast<uint2*>(&pl[w][iloc][jb]) = pw;
            }
        }

        // ---- PV: O^T += V^T * P^T ----
        #pragma unroll
        for (int kc = 0; kc < 2; ++kc) {
            bf16x8 pf[4], vf[2];
            #pragma unroll
            for (int n = 0; n < 4; ++n) {
                int iloc = 16 * n + ll;
                pf[n] = *reinterpret_cast<const bf16x8*>(&pl[w][iloc][(8 * lg + 32 * kc) ^ (8 * (iloc & 7))]);
            }
            #pragma unroll
            for (int dm = 0; dm < 2; ++dm) {
                int d = 16 * dm + ll;
                vf[dm] = *reinterpret_cast<const bf16x8*>(&vt[d][(jt * 64 + 32 * kc + 8 * lg) ^ (8 * (ll & 7))]);
            }
            #pragma unroll
            for (int dm = 0; dm < 2; ++dm)
                #pragma unroll
                for (int n = 0; n < 4; ++n)
                    oacc[dm][n] = __builtin_amdgcn_mfma_f32_16x16x32_bf16(vf[dm], pf[n], oacc[dm][n], 0, 0, 0);
        }
    }

    // ---- epilogue: normalize, gate, store (rows d, cols i) ----
    #pragma unroll
    for (int n = 0; n < 4; ++n) {
        float inv = 1.f / l_run[n];
        size_t prow = base + (size_t)(w * 64 + 16 * n + ll) * CH;
        #pragma unroll
        for (int dm = 0; dm < 2; ++dm) {
            int d0 = 16 * dm + 4 * lg;
            uint2 gu = *reinterpret_cast<const uint2*>(gg + prow + d0);
            float g0 = lo_f(gu.x), g1 = hi_f(gu.x), g2 = lo_f(gu.y), g3 = hi_f(gu.y);
            uint2 ow;
            ow.x = pk2(oacc[dm][n][0] * inv * g0, oacc[dm][n][1] * inv * g1);
            ow.y = pk2(oacc[dm][n][2] * inv * g2, oacc[dm][n][3] * inv * g3);
            *reinterpret_cast<uint2*>(attn + prow + d0) = ow;
        }
    }
}

// ---------------- Kernel 3: output projection (f32 out) ----------------
__global__ __launch_bounds__(256) void out_kernel(const bf16* __restrict__ ga,
                                                  const float* __restrict__ wo,
                                                  const float* __restrict__ bo,
                                                  float* __restrict__ out) {
    __shared__ float xs[32][CH];
    int t = threadIdx.x;
    size_t pbase = (size_t)blockIdx.x * 32;

    for (int l = 0; l < 2; ++l) {
        int e = (l * 256 + t) * 8;
        uint4 u = *reinterpret_cast<const uint4*>(ga + pbase * CH + e);
        int px = e >> 7, c = e & 127;
        xs[px][c + 0] = lo_f(u.x); xs[px][c + 1] = hi_f(u.x);
        xs[px][c + 2] = lo_f(u.y); xs[px][c + 3] = hi_f(u.y);
        xs[px][c + 4] = lo_f(u.z); xs[px][c + 5] = hi_f(u.z);
        xs[px][c + 6] = lo_f(u.w); xs[px][c + 7] = hi_f(u.w);
    }
    __syncthreads();

    int o   = t & 127;
    int px0 = t >> 7;
    const float* W = wo + (size_t)o * CH;
    float acc[16];
    #pragma unroll
    for (int i = 0; i < 16; ++i) acc[i] = 0.f;
    for (int c0 = 0; c0 < CH; c0 += 4) {
        float4 w4 = *reinterpret_cast<const float4*>(W + c0);
        #pragma unroll
        for (int i = 0; i < 16; ++i) {
            int px = px0 + 2 * i;
            acc[i] += xs[px][c0] * w4.x + xs[px][c0 + 1] * w4.y
                    + xs[px][c0 + 2] * w4.z + xs[px][c0 + 3] * w4.w;
        }
    }
    float bov = bo[o];
    #pragma unroll
    for (int i = 0; i < 16; ++i) {
        int px = px0 + 2 * i;
        out[(pbase + px) * CH + o] = acc[i] + bov;
    }
}

extern "C" void kernel_launch(void* const* d_in, const int* in_sizes, int n_in,
                              void* d_out, int out_size, void* d_ws, size_t ws_size,
                              hipStream_t stream) {
    const float* x2d = (const float*)d_in[0];
    const float* nw  = (const float*)d_in[1];
    const float* nb  = (const float*)d_in[2];
    const float* wq  = (const float*)d_in[3];
    const float* wk  = (const float*)d_in[4];
    const float* wv  = (const float*)d_in[5];
    const float* wb  = (const float*)d_in[6];
    const float* wg  = (const float*)d_in[7];
    const float* bg  = (const float*)d_in[8];
    const float* wo  = (const float*)d_in[9];
    const float* bo  = (const float*)d_in[10];
    float* out = (float*)d_out;

    float* bias = (float*)d_ws;
    bf16*  q    = (bf16*)((float*)d_ws + (size_t)NH * NPX);
    bf16*  k    = q + (size_t)NPX * CH;
    bf16*  v    = k + (size_t)NPX * CH;
    bf16*  g    = v + (size_t)NPX * CH;

    proj_kernel<<<NPX / 32, 256, 0, stream>>>(x2d, nw, nb, wq, wk, wv, wg, bg, wb,
                                              q, k, v, g, bias);
    attn_kernel<<<dim3(NRES, NH), 256, 0, stream>>>(q, k, v, bias, g, q);
    out_kernel<<<NPX / 32, 256, 0, stream>>>(q, wo, bo, out);
}

// Round 4
// 128.301 us; speedup vs baseline: 4.2508x; 2.6869x over previous
//
#include <hip/hip_runtime.h>
#include <hip/hip_bf16.h>

#define NRES 256
#define CH   128
#define NH   4
#define HD   32
#define NPX  (NRES*NRES)   // 65536 pixels
#define BPX  64            // pixels per block in GEMM kernels

typedef __hip_bfloat16 bf16;
typedef __attribute__((ext_vector_type(8))) short bf16x8;
typedef __attribute__((ext_vector_type(4))) float f32x4;

__device__ __forceinline__ float lo_f(unsigned u) { return __uint_as_float(u << 16); }
__device__ __forceinline__ float hi_f(unsigned u) { return __uint_as_float(u & 0xffff0000u); }
__device__ __forceinline__ unsigned pk2(float a, float b) {
    unsigned short ua = __bfloat16_as_ushort(__float2bfloat16(a));
    unsigned short ub = __bfloat16_as_ushort(__float2bfloat16(b));
    return (unsigned)ua | ((unsigned)ub << 16);
}

// ---------------- Kernel 0: convert weights f32 -> bf16 ----------------
// dst: [wq | wk | wv | wg | wo], each 128x128 row-major
__global__ __launch_bounds__(256) void prep_kernel(const float* __restrict__ wq,
                                                   const float* __restrict__ wk,
                                                   const float* __restrict__ wv,
                                                   const float* __restrict__ wg,
                                                   const float* __restrict__ wo,
                                                   bf16* __restrict__ dst) {
    int mat = blockIdx.x >> 4;                       // 16 blocks per matrix
    int off = ((blockIdx.x & 15) * 256 + threadIdx.x) * 4;
    const float* srcs[5] = {wq, wk, wv, wg, wo};
    float4 v4 = *reinterpret_cast<const float4*>(srcs[mat] + off);
    uint2 o;
    o.x = pk2(v4.x, v4.y);
    o.y = pk2(v4.z, v4.w);
    *reinterpret_cast<uint2*>(dst + (size_t)mat * 16384 + off) = o;
}

// ---------------- Kernel 1: LN + MFMA projections q,k,v,g + pair bias ----------------
// 64 pixels/block, 4 waves; wave w owns 2 n-tiles (32 outputs) x 4 m-tiles (64 px)
__global__ __launch_bounds__(256) void proj_kernel(const float* __restrict__ x2d,
                                                   const float* __restrict__ nw,
                                                   const float* __restrict__ nb,
                                                   const bf16* __restrict__ wgt,  // [wq|wk|wv|wg] bf16
                                                   const float* __restrict__ bg,
                                                   const float* __restrict__ wb,
                                                   bf16* __restrict__ q,
                                                   bf16* __restrict__ k,
                                                   bf16* __restrict__ v,
                                                   bf16* __restrict__ g,
                                                   float* __restrict__ bias) {
    __shared__ float xs32[BPX][132];   // padded f32 normed x (33 KB)
    __shared__ short xsb[BPX][128];    // XOR-swizzled bf16 normed x (16 KB)
    __shared__ float nwl[128], nbl[128];

    int t = threadIdx.x;
    size_t pbase = (size_t)blockIdx.x * BPX;

    if (t < 32) {
        *reinterpret_cast<float4*>(&nwl[t * 4]) = *reinterpret_cast<const float4*>(nw + t * 4);
        *reinterpret_cast<float4*>(&nbl[t * 4]) = *reinterpret_cast<const float4*>(nb + t * 4);
    }
    for (int it = 0; it < 8; ++it) {
        int idx = (it * 256 + t) * 4;
        int px = idx >> 7, c = idx & 127;
        *reinterpret_cast<float4*>(&xs32[px][c]) =
            *reinterpret_cast<const float4*>(x2d + pbase * CH + idx);
    }
    __syncthreads();

    // LayerNorm: 4 threads per pixel, stride-4 channels
    {
        int px = t >> 2, lo = t & 3;
        float vals[32];
        float s = 0.f, ss = 0.f;
        #pragma unroll
        for (int cc = 0; cc < 32; ++cc) {
            float x = xs32[px][lo + 4 * cc];
            vals[cc] = x; s += x; ss += x * x;
        }
        s += __shfl_xor(s, 1); ss += __shfl_xor(ss, 1);
        s += __shfl_xor(s, 2); ss += __shfl_xor(ss, 2);
        float mu  = s * (1.0f / CH);
        float var = ss * (1.0f / CH) - mu * mu;
        float rs  = rsqrtf(var + 1e-5f);
        #pragma unroll
        for (int cc = 0; cc < 32; ++cc) {
            int c = lo + 4 * cc;
            float xv = (vals[cc] - mu) * rs * nwl[c] + nbl[c];
            xs32[px][c] = xv;
            int sc = ((((c >> 3) ^ px) & 7) << 3) | (c & 7) | (c & 64);  // swizzle low 3 granule bits
            xsb[px][sc] = (short)__bfloat16_as_ushort(__float2bfloat16(xv));
        }
    }
    __syncthreads();

    int w  = t >> 6, l = t & 63;
    int ll = l & 15, lg = l >> 4;
    bf16* Os[4] = {q, k, v, g};
    const float qscale = 0.17677669529663689f;   // 1/sqrt(32)

    #pragma unroll
    for (int mat = 0; mat < 4; ++mat) {
        const bf16* W = wgt + (size_t)mat * 16384;
        bf16x8 bfr[2][4];
        #pragma unroll
        for (int p = 0; p < 2; ++p)
            #pragma unroll
            for (int kt = 0; kt < 4; ++kt)
                bfr[p][kt] = *reinterpret_cast<const bf16x8*>(
                    W + (size_t)((2 * w + p) * 16 + ll) * CH + kt * 32 + lg * 8);

        f32x4 acc[4][2];
        #pragma unroll
        for (int mt = 0; mt < 4; ++mt)
            #pragma unroll
            for (int p = 0; p < 2; ++p) acc[mt][p] = (f32x4){0.f, 0.f, 0.f, 0.f};

        #pragma unroll
        for (int kt = 0; kt < 4; ++kt) {
            bf16x8 a[4];
            #pragma unroll
            for (int mt = 0; mt < 4; ++mt) {
                int row = 16 * mt + ll;
                int gr  = (kt * 4 + lg) ^ (row & 7);
                a[mt] = *reinterpret_cast<const bf16x8*>(&xsb[row][gr * 8]);
            }
            #pragma unroll
            for (int mt = 0; mt < 4; ++mt)
                #pragma unroll
                for (int p = 0; p < 2; ++p)
                    acc[mt][p] = __builtin_amdgcn_mfma_f32_16x16x32_bf16(a[mt], bfr[p][kt], acc[mt][p], 0, 0, 0);
        }

        #pragma unroll
        for (int p = 0; p < 2; ++p) {
            int o = (2 * w + p) * 16 + ll;
            float bgv = (mat == 3) ? bg[o] : 0.f;
            #pragma unroll
            for (int mt = 0; mt < 4; ++mt) {
                #pragma unroll
                for (int r = 0; r < 4; ++r) {
                    int prow = 16 * mt + lg * 4 + r;
                    float valf = acc[mt][p][r];
                    if (mat == 0) valf *= qscale;
                    if (mat == 3) valf = 1.f / (1.f + __expf(-(valf + bgv)));
                    Os[mat][(pbase + prow) * CH + o] = __float2bfloat16(valf);
                }
            }
        }
    }

    // pair bias (f32 path): bias[h][px] = sum_c xn[px][c] * wb[h][c]
    {
        int px = t >> 2, h = t & 3;
        float a = 0.f;
        for (int c = 0; c < CH; ++c) a += xs32[px][c] * wb[h * CH + c];
        bias[(size_t)h * NPX + pbase + px] = a;
    }
}

// ---------------- Kernel 2: MFMA flash attention per (m,h) ----------------
__global__ __launch_bounds__(256) void attn_kernel(const bf16* q,
                                                   const bf16* __restrict__ kk,
                                                   const bf16* __restrict__ vv,
                                                   const float* __restrict__ bias,
                                                   const bf16* __restrict__ gg,
                                                   bf16* attn) {
    __shared__ short kl[NRES][HD];
    __shared__ short vt[HD][NRES];
    __shared__ short pl[4][64][64];

    int t  = threadIdx.x;
    int w  = t >> 6;
    int l  = t & 63;
    int lg = l >> 4;
    int ll = l & 15;
    int m = blockIdx.x, h = blockIdx.y;
    size_t base = ((size_t)m * NRES) * CH + (size_t)h * HD;

    for (int it = 0; it < 4; ++it) {
        int e8 = t + 256 * it;
        int j  = e8 >> 2;
        int d0 = (e8 & 3) * 8;
        uint4 ku = *reinterpret_cast<const uint4*>(kk + base + (size_t)j * CH + d0);
        *reinterpret_cast<uint4*>(&kl[j][d0 ^ (8 * ((j >> 1) & 3))]) = ku;
        uint4 vu = *reinterpret_cast<const uint4*>(vv + base + (size_t)j * CH + d0);
        union { uint4 u; short s[8]; } vc; vc.u = vu;
        #pragma unroll
        for (int s = 0; s < 8; ++s)
            vt[d0 + s][j ^ (8 * s)] = vc.s[s];
    }

    bf16x8 qf[4];
    #pragma unroll
    for (int n = 0; n < 4; ++n)
        qf[n] = *reinterpret_cast<const bf16x8*>(q + base + (size_t)(w * 64 + 16 * n + ll) * CH + 8 * lg);

    __syncthreads();

    float m_run[4], l_run[4];
    f32x4 oacc[2][4];
    #pragma unroll
    for (int n = 0; n < 4; ++n) { m_run[n] = -1e30f; l_run[n] = 0.f; }
    #pragma unroll
    for (int dm = 0; dm < 2; ++dm)
        #pragma unroll
        for (int n = 0; n < 4; ++n) oacc[dm][n] = (f32x4){0.f, 0.f, 0.f, 0.f};

    for (int jt = 0; jt < 4; ++jt) {
        f32x4 sacc[4][4];
        #pragma unroll
        for (int mj = 0; mj < 4; ++mj)
            #pragma unroll
            for (int n = 0; n < 4; ++n) sacc[mj][n] = (f32x4){0.f, 0.f, 0.f, 0.f};

        #pragma unroll
        for (int mj = 0; mj < 4; ++mj) {
            int jrow = jt * 64 + 16 * mj + ll;
            bf16x8 kf = *reinterpret_cast<const bf16x8*>(&kl[jrow][(8 * lg) ^ (8 * ((jrow >> 1) & 3))]);
            #pragma unroll
            for (int n = 0; n < 4; ++n)
                sacc[mj][n] = __builtin_amdgcn_mfma_f32_16x16x32_bf16(kf, qf[n], sacc[mj][n], 0, 0, 0);
        }

        #pragma unroll
        for (int n = 0; n < 4; ++n) {
            int i = w * 64 + 16 * n + ll;
            #pragma unroll
            for (int mj = 0; mj < 4; ++mj) {
                float4 b4 = *reinterpret_cast<const float4*>(bias + (size_t)h * NPX + (size_t)i * NRES + jt * 64 + 16 * mj + 4 * lg);
                sacc[mj][n][0] += b4.x; sacc[mj][n][1] += b4.y;
                sacc[mj][n][2] += b4.z; sacc[mj][n][3] += b4.w;
            }
        }

        #pragma unroll
        for (int n = 0; n < 4; ++n) {
            float mx = -1e30f;
            #pragma unroll
            for (int mj = 0; mj < 4; ++mj)
                #pragma unroll
                for (int r = 0; r < 4; ++r) mx = fmaxf(mx, sacc[mj][n][r]);
            mx = fmaxf(mx, __shfl_xor(mx, 16));
            mx = fmaxf(mx, __shfl_xor(mx, 32));
            float mnew  = fmaxf(m_run[n], mx);
            float scale = __expf(m_run[n] - mnew);
            l_run[n] *= scale;
            #pragma unroll
            for (int dm = 0; dm < 2; ++dm)
                #pragma unroll
                for (int r = 0; r < 4; ++r) oacc[dm][n][r] *= scale;
            m_run[n] = mnew;

            float psum = 0.f;
            #pragma unroll
            for (int mj = 0; mj < 4; ++mj) {
                #pragma unroll
                for (int r = 0; r < 4; ++r) {
                    float p = __expf(sacc[mj][n][r] - mnew);
                    sacc[mj][n][r] = p;
                    psum += p;
                }
            }
            psum += __shfl_xor(psum, 16);
            psum += __shfl_xor(psum, 32);
            l_run[n] += psum;

            int iloc = 16 * n + ll;
            #pragma unroll
            for (int mj = 0; mj < 4; ++mj) {
                int jb = (16 * mj + 4 * lg) ^ (8 * (iloc & 7));
                uint2 pw;
                pw.x = pk2(sacc[mj][n][0], sacc[mj][n][1]);
                pw.y = pk2(sacc[mj][n][2], sacc[mj][n][3]);
                *reinterpret_cast<uint2*>(&pl[w][iloc][jb]) = pw;
            }
        }

        #pragma unroll
        for (int kc = 0; kc < 2; ++kc) {
            bf16x8 pf[4], vf[2];
            #pragma unroll
            for (int n = 0; n < 4; ++n) {
                int iloc = 16 * n + ll;
                pf[n] = *reinterpret_cast<const bf16x8*>(&pl[w][iloc][(8 * lg + 32 * kc) ^ (8 * (iloc & 7))]);
            }
            #pragma unroll
            for (int dm = 0; dm < 2; ++dm) {
                int d = 16 * dm + ll;
                vf[dm] = *reinterpret_cast<const bf16x8*>(&vt[d][(jt * 64 + 32 * kc + 8 * lg) ^ (8 * (ll & 7))]);
            }
            #pragma unroll
            for (int dm = 0; dm < 2; ++dm)
                #pragma unroll
                for (int n = 0; n < 4; ++n)
                    oacc[dm][n] = __builtin_amdgcn_mfma_f32_16x16x32_bf16(vf[dm], pf[n], oacc[dm][n], 0, 0, 0);
        }
    }

    #pragma unroll
    for (int n = 0; n < 4; ++n) {
        float inv = 1.f / l_run[n];
        size_t prow = base + (size_t)(w * 64 + 16 * n + ll) * CH;
        #pragma unroll
        for (int dm = 0; dm < 2; ++dm) {
            int d0 = 16 * dm + 4 * lg;
            uint2 gu = *reinterpret_cast<const uint2*>(gg + prow + d0);
            float g0 = lo_f(gu.x), g1 = hi_f(gu.x), g2 = lo_f(gu.y), g3 = hi_f(gu.y);
            uint2 ow;
            ow.x = pk2(oacc[dm][n][0] * inv * g0, oacc[dm][n][1] * inv * g1);
            ow.y = pk2(oacc[dm][n][2] * inv * g2, oacc[dm][n][3] * inv * g3);
            *reinterpret_cast<uint2*>(attn + prow + d0) = ow;
        }
    }
}

// ---------------- Kernel 3: MFMA output projection (f32 out) ----------------
__global__ __launch_bounds__(256) void out_kernel(const bf16* __restrict__ ga,
                                                  const bf16* __restrict__ wob,
                                                  const float* __restrict__ bo,
                                                  float* __restrict__ out) {
    __shared__ short xsb[BPX][128];
    int t = threadIdx.x;
    size_t pbase = (size_t)blockIdx.x * BPX;

    for (int it = 0; it < 4; ++it) {
        int idx = (it * 256 + t) * 8;
        int px = idx >> 7, c = idx & 127;
        int gr = c >> 3;
        uint4 u = *reinterpret_cast<const uint4*>(ga + pbase * CH + idx);
        *reinterpret_cast<uint4*>(&xsb[px][(gr ^ (px & 7)) * 8]) = u;
    }
    __syncthreads();

    int w  = t >> 6, l = t & 63;
    int ll = l & 15, lg = l >> 4;

    bf16x8 bfr[2][4];
    #pragma unroll
    for (int p = 0; p < 2; ++p)
        #pragma unroll
        for (int kt = 0; kt < 4; ++kt)
            bfr[p][kt] = *reinterpret_cast<const bf16x8*>(
                wob + (size_t)((2 * w + p) * 16 + ll) * CH + kt * 32 + lg * 8);

    f32x4 acc[4][2];
    #pragma unroll
    for (int mt = 0; mt < 4; ++mt)
        #pragma unroll
        for (int p = 0; p < 2; ++p) acc[mt][p] = (f32x4){0.f, 0.f, 0.f, 0.f};

    #pragma unroll
    for (int kt = 0; kt < 4; ++kt) {
        bf16x8 a[4];
        #pragma unroll
        for (int mt = 0; mt < 4; ++mt) {
            int row = 16 * mt + ll;
            int gr  = (kt * 4 + lg) ^ (row & 7);
            a[mt] = *reinterpret_cast<const bf16x8*>(&xsb[row][gr * 8]);
        }
        #pragma unroll
        for (int mt = 0; mt < 4; ++mt)
            #pragma unroll
            for (int p = 0; p < 2; ++p)
                acc[mt][p] = __builtin_amdgcn_mfma_f32_16x16x32_bf16(a[mt], bfr[p][kt], acc[mt][p], 0, 0, 0);
    }

    #pragma unroll
    for (int p = 0; p < 2; ++p) {
        int o = (2 * w + p) * 16 + ll;
        float bov = bo[o];
        #pragma unroll
        for (int mt = 0; mt < 4; ++mt)
            #pragma unroll
            for (int r = 0; r < 4; ++r) {
                int prow = 16 * mt + lg * 4 + r;
                out[(pbase + prow) * CH + o] = acc[mt][p][r] + bov;
            }
    }
}

extern "C" void kernel_launch(void* const* d_in, const int* in_sizes, int n_in,
                              void* d_out, int out_size, void* d_ws, size_t ws_size,
                              hipStream_t stream) {
    const float* x2d = (const float*)d_in[0];
    const float* nw  = (const float*)d_in[1];
    const float* nb  = (const float*)d_in[2];
    const float* wq  = (const float*)d_in[3];
    const float* wk  = (const float*)d_in[4];
    const float* wv  = (const float*)d_in[5];
    const float* wb  = (const float*)d_in[6];
    const float* wg  = (const float*)d_in[7];
    const float* bg  = (const float*)d_in[8];
    const float* wo  = (const float*)d_in[9];
    const float* bo  = (const float*)d_in[10];
    float* out = (float*)d_out;

    float* bias = (float*)d_ws;                                  // 1 MB
    bf16*  q    = (bf16*)((float*)d_ws + (size_t)NH * NPX);
    bf16*  k    = q + (size_t)NPX * CH;
    bf16*  v    = k + (size_t)NPX * CH;
    bf16*  g    = v + (size_t)NPX * CH;
    bf16*  wgt  = g + (size_t)NPX * CH;                          // 5 x 128x128 bf16
    bf16*  wob  = wgt + 4 * 16384;

    prep_kernel<<<80, 256, 0, stream>>>(wq, wk, wv, wg, wo, wgt);
    proj_kernel<<<NPX / BPX, 256, 0, stream>>>(x2d, nw, nb, wgt, bg, wb, q, k, v, g, bias);
    attn_kernel<<<dim3(NRES, NH), 256, 0, stream>>>(q, k, v, bias, g, q);
    out_kernel<<<NPX / BPX, 256, 0, stream>>>(q, wob, bo, out);
}

// Round 6
// 118.471 us; speedup vs baseline: 4.6035x; 1.0830x over previous
//
#include <hip/hip_runtime.h>
#include <hip/hip_bf16.h>

#define NRES 256
#define CH   128
#define NH   4
#define HD   32
#define NPX  (NRES*NRES)   // 65536 pixels
#define BPX  64            // pixels per block in GEMM kernels
#define LOG2E 1.4426950408889634f

typedef __hip_bfloat16 bf16;
typedef __attribute__((ext_vector_type(8))) short bf16x8;
typedef __attribute__((ext_vector_type(4))) float f32x4;

__device__ __forceinline__ float lo_f(unsigned u) { return __uint_as_float(u << 16); }
__device__ __forceinline__ float hi_f(unsigned u) { return __uint_as_float(u & 0xffff0000u); }
__device__ __forceinline__ float fexp2(float x) { return __builtin_amdgcn_exp2f(x); }
__device__ __forceinline__ unsigned pk2(float a, float b) {
    unsigned short ua = __bfloat16_as_ushort(__float2bfloat16(a));
    unsigned short ub = __bfloat16_as_ushort(__float2bfloat16(b));
    return (unsigned)ua | ((unsigned)ub << 16);
}

// ---------------- Kernel 0: convert weights f32 -> bf16 ----------------
__global__ __launch_bounds__(256) void prep_kernel(const float* __restrict__ wq,
                                                   const float* __restrict__ wk,
                                                   const float* __restrict__ wv,
                                                   const float* __restrict__ wg,
                                                   const float* __restrict__ wo,
                                                   bf16* __restrict__ dst) {
    int mat = blockIdx.x >> 4;
    int off = ((blockIdx.x & 15) * 256 + threadIdx.x) * 4;
    const float* srcs[5] = {wq, wk, wv, wg, wo};
    float4 v4 = *reinterpret_cast<const float4*>(srcs[mat] + off);
    uint2 o;
    o.x = pk2(v4.x, v4.y);
    o.y = pk2(v4.z, v4.w);
    *reinterpret_cast<uint2*>(dst + (size_t)mat * 16384 + off) = o;
}

// ---------------- Kernel 1: LN + MFMA projections q,k,v,g + pair bias ----------------
__global__ __launch_bounds__(256) void proj_kernel(const float* __restrict__ x2d,
                                                   const float* __restrict__ nw,
                                                   const float* __restrict__ nb,
                                                   const bf16* __restrict__ wgt,
                                                   const float* __restrict__ bg,
                                                   const float* __restrict__ wb,
                                                   bf16* __restrict__ q,
                                                   bf16* __restrict__ k,
                                                   bf16* __restrict__ v,
                                                   bf16* __restrict__ g,
                                                   float* __restrict__ bias) {
    __shared__ float xs32[BPX][132];
    __shared__ short xsb[BPX][128];
    __shared__ float nwl[128], nbl[128];

    int t = threadIdx.x;
    size_t pbase = (size_t)blockIdx.x * BPX;

    if (t < 32) {
        *reinterpret_cast<float4*>(&nwl[t * 4]) = *reinterpret_cast<const float4*>(nw + t * 4);
        *reinterpret_cast<float4*>(&nbl[t * 4]) = *reinterpret_cast<const float4*>(nb + t * 4);
    }
    for (int it = 0; it < 8; ++it) {
        int idx = (it * 256 + t) * 4;
        int px = idx >> 7, c = idx & 127;
        *reinterpret_cast<float4*>(&xs32[px][c]) =
            *reinterpret_cast<const float4*>(x2d + pbase * CH + idx);
    }
    __syncthreads();

    {
        int px = t >> 2, lo = t & 3;
        float vals[32];
        float s = 0.f, ss = 0.f;
        #pragma unroll
        for (int cc = 0; cc < 32; ++cc) {
            float x = xs32[px][lo + 4 * cc];
            vals[cc] = x; s += x; ss += x * x;
        }
        s += __shfl_xor(s, 1); ss += __shfl_xor(ss, 1);
        s += __shfl_xor(s, 2); ss += __shfl_xor(ss, 2);
        float mu  = s * (1.0f / CH);
        float var = ss * (1.0f / CH) - mu * mu;
        float rs  = rsqrtf(var + 1e-5f);
        #pragma unroll
        for (int cc = 0; cc < 32; ++cc) {
            int c = lo + 4 * cc;
            float xv = (vals[cc] - mu) * rs * nwl[c] + nbl[c];
            xs32[px][c] = xv;
            int sc = ((((c >> 3) ^ px) & 7) << 3) | (c & 7) | (c & 64);
            xsb[px][sc] = (short)__bfloat16_as_ushort(__float2bfloat16(xv));
        }
    }
    __syncthreads();

    int w  = t >> 6, l = t & 63;
    int ll = l & 15, lg = l >> 4;
    bf16* Os[4] = {q, k, v, g};
    const float qscale = 0.17677669529663689f * LOG2E;   // 1/sqrt(32) * log2(e)

    #pragma unroll
    for (int mat = 0; mat < 4; ++mat) {
        const bf16* W = wgt + (size_t)mat * 16384;
        bf16x8 bfr[2][4];
        #pragma unroll
        for (int p = 0; p < 2; ++p)
            #pragma unroll
            for (int kt = 0; kt < 4; ++kt)
                bfr[p][kt] = *reinterpret_cast<const bf16x8*>(
                    W + (size_t)((2 * w + p) * 16 + ll) * CH + kt * 32 + lg * 8);

        f32x4 acc[4][2];
        #pragma unroll
        for (int mt = 0; mt < 4; ++mt)
            #pragma unroll
            for (int p = 0; p < 2; ++p) acc[mt][p] = (f32x4){0.f, 0.f, 0.f, 0.f};

        #pragma unroll
        for (int kt = 0; kt < 4; ++kt) {
            bf16x8 a[4];
            #pragma unroll
            for (int mt = 0; mt < 4; ++mt) {
                int row = 16 * mt + ll;
                int gr  = (kt * 4 + lg) ^ (row & 7);
                a[mt] = *reinterpret_cast<const bf16x8*>(&xsb[row][gr * 8]);
            }
            #pragma unroll
            for (int mt = 0; mt < 4; ++mt)
                #pragma unroll
                for (int p = 0; p < 2; ++p)
                    acc[mt][p] = __builtin_amdgcn_mfma_f32_16x16x32_bf16(a[mt], bfr[p][kt], acc[mt][p], 0, 0, 0);
        }

        #pragma unroll
        for (int p = 0; p < 2; ++p) {
            int o = (2 * w + p) * 16 + ll;
            float bgv = (mat == 3) ? bg[o] : 0.f;
            #pragma unroll
            for (int mt = 0; mt < 4; ++mt) {
                #pragma unroll
                for (int r = 0; r < 4; ++r) {
                    int prow = 16 * mt + lg * 4 + r;
                    float valf = acc[mt][p][r];
                    if (mat == 0) valf *= qscale;
                    if (mat == 3) valf = 1.f / (1.f + __expf(-(valf + bgv)));
                    Os[mat][(pbase + prow) * CH + o] = __float2bfloat16(valf);
                }
            }
        }
    }

    {
        int px = t >> 2, h = t & 3;
        float a = 0.f;
        for (int c = 0; c < CH; ++c) a += xs32[px][c] * wb[h * CH + c];
        bias[(size_t)h * NPX + pbase + px] = a * LOG2E;
    }
}

// ---------------- Kernel 2: MFMA flash attention per (m,h) ----------------
// 4 waves x 64 query rows; j in 32-wide tiles; K direct from global; exp2 domain
__global__ __launch_bounds__(256, 4) void attn_kernel(const bf16* q,
                                                      const bf16* __restrict__ kk,
                                                      const bf16* __restrict__ vv,
                                                      const float* __restrict__ bias,
                                                      const bf16* __restrict__ gg,
                                                      bf16* attn) {
    __shared__ short vt[HD][NRES];     // 16 KB, transposed V, swizzled
    __shared__ short pl[4][64][32];    // 16 KB, per-wave P half-tile

    int t  = threadIdx.x;
    int w  = t >> 6;
    int l  = t & 63;
    int lg = l >> 4;
    int ll = l & 15;
    int m = blockIdx.x, h = blockIdx.y;
    size_t base = ((size_t)m * NRES) * CH + (size_t)h * HD;

    // stage V transposed + swizzled
    for (int it = 0; it < 4; ++it) {
        int e8 = t + 256 * it;
        int j  = e8 >> 2;
        int d0 = (e8 & 3) * 8;
        uint4 vu = *reinterpret_cast<const uint4*>(vv + base + (size_t)j * CH + d0);
        union { uint4 u; short s[8]; } vc; vc.u = vu;
        #pragma unroll
        for (int s = 0; s < 8; ++s)
            vt[d0 + s][j ^ (8 * s)] = vc.s[s];
    }

    bf16x8 qf[4];
    #pragma unroll
    for (int n = 0; n < 4; ++n)
        qf[n] = *reinterpret_cast<const bf16x8*>(q + base + (size_t)(w * 64 + 16 * n + ll) * CH + 8 * lg);

    __syncthreads();

    float m_run[4], l_run[4];
    f32x4 oacc[2][4];
    #pragma unroll
    for (int n = 0; n < 4; ++n) { m_run[n] = -1e30f; l_run[n] = 0.f; }
    #pragma unroll
    for (int dm = 0; dm < 2; ++dm)
        #pragma unroll
        for (int n = 0; n < 4; ++n) oacc[dm][n] = (f32x4){0.f, 0.f, 0.f, 0.f};

    const float* bh = bias + (size_t)h * NPX;

    for (int jt = 0; jt < 8; ++jt) {
        int j0 = jt * 32;

        // K fragments direct from global (L1/L2-served, read once)
        bf16x8 kf[2];
        #pragma unroll
        for (int mj = 0; mj < 2; ++mj)
            kf[mj] = *reinterpret_cast<const bf16x8*>(kk + base + (size_t)(j0 + 16 * mj + ll) * CH + 8 * lg);

        f32x4 sacc[2][4];
        #pragma unroll
        for (int mj = 0; mj < 2; ++mj)
            #pragma unroll
            for (int n = 0; n < 4; ++n) sacc[mj][n] = (f32x4){0.f, 0.f, 0.f, 0.f};

        __builtin_amdgcn_s_setprio(1);
        #pragma unroll
        for (int mj = 0; mj < 2; ++mj)
            #pragma unroll
            for (int n = 0; n < 4; ++n)
                sacc[mj][n] = __builtin_amdgcn_mfma_f32_16x16x32_bf16(kf[mj], qf[n], sacc[mj][n], 0, 0, 0);
        __builtin_amdgcn_s_setprio(0);

        // bias add (already in exp2 domain)
        #pragma unroll
        for (int n = 0; n < 4; ++n) {
            int i = w * 64 + 16 * n + ll;
            #pragma unroll
            for (int mj = 0; mj < 2; ++mj) {
                float4 b4 = *reinterpret_cast<const float4*>(bh + (size_t)i * NRES + j0 + 16 * mj + 4 * lg);
                sacc[mj][n][0] += b4.x; sacc[mj][n][1] += b4.y;
                sacc[mj][n][2] += b4.z; sacc[mj][n][3] += b4.w;
            }
        }

        // online softmax per i (exp2 domain) + pack P half-tile
        #pragma unroll
        for (int n = 0; n < 4; ++n) {
            float mx = fmaxf(fmaxf(fmaxf(sacc[0][n][0], sacc[0][n][1]), fmaxf(sacc[0][n][2], sacc[0][n][3])),
                             fmaxf(fmaxf(sacc[1][n][0], sacc[1][n][1]), fmaxf(sacc[1][n][2], sacc[1][n][3])));
            mx = fmaxf(mx, __shfl_xor(mx, 16));
            mx = fmaxf(mx, __shfl_xor(mx, 32));
            float mnew  = fmaxf(m_run[n], mx);
            float scale = fexp2(m_run[n] - mnew);
            l_run[n] *= scale;
            #pragma unroll
            for (int dm = 0; dm < 2; ++dm)
                #pragma unroll
                for (int r = 0; r < 4; ++r) oacc[dm][n][r] *= scale;
            m_run[n] = mnew;

            float psum = 0.f;
            #pragma unroll
            for (int mj = 0; mj < 2; ++mj) {
                #pragma unroll
                for (int r = 0; r < 4; ++r) {
                    float p = fexp2(sacc[mj][n][r] - mnew);
                    sacc[mj][n][r] = p;
                    psum += p;
                }
            }
            psum += __shfl_xor(psum, 16);
            psum += __shfl_xor(psum, 32);
            l_run[n] += psum;

            int iloc = 16 * n + ll;
            #pragma unroll
            for (int mj = 0; mj < 2; ++mj) {
                int jb  = 16 * mj + 4 * lg;
                int off = ((jb >> 3) ^ (iloc & 3)) * 8 + (jb & 7);   // granule XOR swizzle
                uint2 pw;
                pw.x = pk2(sacc[mj][n][0], sacc[mj][n][1]);
                pw.y = pk2(sacc[mj][n][2], sacc[mj][n][3]);
                *reinterpret_cast<uint2*>(&pl[w][iloc][off]) = pw;
            }
        }

        // PV: O^T += V^T * P^T (single 32-wide k-chunk)
        bf16x8 pf[4], vf[2];
        #pragma unroll
        for (int n = 0; n < 4; ++n) {
            int iloc = 16 * n + ll;
            int gr   = lg ^ (iloc & 3);
            pf[n] = *reinterpret_cast<const bf16x8*>(&pl[w][iloc][gr * 8]);
        }
        #pragma unroll
        for (int dm = 0; dm < 2; ++dm) {
            int d = 16 * dm + ll;
            vf[dm] = *reinterpret_cast<const bf16x8*>(&vt[d][(j0 + 8 * lg) ^ (8 * (ll & 7))]);
        }
        __builtin_amdgcn_s_setprio(1);
        #pragma unroll
        for (int dm = 0; dm < 2; ++dm)
            #pragma unroll
            for (int n = 0; n < 4; ++n)
                oacc[dm][n] = __builtin_amdgcn_mfma_f32_16x16x32_bf16(vf[dm], pf[n], oacc[dm][n], 0, 0, 0);
        __builtin_amdgcn_s_setprio(0);
    }

    // epilogue: normalize, gate, store
    #pragma unroll
    for (int n = 0; n < 4; ++n) {
        float inv = 1.f / l_run[n];
        size_t prow = base + (size_t)(w * 64 + 16 * n + ll) * CH;
        #pragma unroll
        for (int dm = 0; dm < 2; ++dm) {
            int d0 = 16 * dm + 4 * lg;
            uint2 gu = *reinterpret_cast<const uint2*>(gg + prow + d0);
            float g0 = lo_f(gu.x), g1 = hi_f(gu.x), g2 = lo_f(gu.y), g3 = hi_f(gu.y);
            uint2 ow;
            ow.x = pk2(oacc[dm][n][0] * inv * g0, oacc[dm][n][1] * inv * g1);
            ow.y = pk2(oacc[dm][n][2] * inv * g2, oacc[dm][n][3] * inv * g3);
            *reinterpret_cast<uint2*>(attn + prow + d0) = ow;
        }
    }
}

// ---------------- Kernel 3: MFMA output projection (f32 out) ----------------
__global__ __launch_bounds__(256) void out_kernel(const bf16* __restrict__ ga,
                                                  const bf16* __restrict__ wob,
                                                  const float* __restrict__ bo,
                                                  float* __restrict__ out) {
    __shared__ short xsb[BPX][128];
    int t = threadIdx.x;
    size_t pbase = (size_t)blockIdx.x * BPX;

    for (int it = 0; it < 4; ++it) {
        int idx = (it * 256 + t) * 8;
        int px = idx >> 7, c = idx & 127;
        int gr = c >> 3;
        uint4 u = *reinterpret_cast<const uint4*>(ga + pbase * CH + idx);
        *reinterpret_cast<uint4*>(&xsb[px][(gr ^ (px & 7)) * 8]) = u;
    }
    __syncthreads();

    int w  = t >> 6, l = t & 63;
    int ll = l & 15, lg = l >> 4;

    bf16x8 bfr[2][4];
    #pragma unroll
    for (int p = 0; p < 2; ++p)
        #pragma unroll
        for (int kt = 0; kt < 4; ++kt)
            bfr[p][kt] = *reinterpret_cast<const bf16x8*>(
                wob + (size_t)((2 * w + p) * 16 + ll) * CH + kt * 32 + lg * 8);

    f32x4 acc[4][2];
    #pragma unroll
    for (int mt = 0; mt < 4; ++mt)
        #pragma unroll
        for (int p = 0; p < 2; ++p) acc[mt][p] = (f32x4){0.f, 0.f, 0.f, 0.f};

    #pragma unroll
    for (int kt = 0; kt < 4; ++kt) {
        bf16x8 a[4];
        #pragma unroll
        for (int mt = 0; mt < 4; ++mt) {
            int row = 16 * mt + ll;
            int gr  = (kt * 4 + lg) ^ (row & 7);
            a[mt] = *reinterpret_cast<const bf16x8*>(&xsb[row][gr * 8]);
        }
        #pragma unroll
        for (int mt = 0; mt < 4; ++mt)
            #pragma unroll
            for (int p = 0; p < 2; ++p)
                acc[mt][p] = __builtin_amdgcn_mfma_f32_16x16x32_bf16(a[mt], bfr[p][kt], acc[mt][p], 0, 0, 0);
    }

    #pragma unroll
    for (int p = 0; p < 2; ++p) {
        int o = (2 * w + p) * 16 + ll;
        float bov = bo[o];
        #pragma unroll
        for (int mt = 0; mt < 4; ++mt)
            #pragma unroll
            for (int r = 0; r < 4; ++r) {
                int prow = 16 * mt + lg * 4 + r;
                out[(pbase + prow) * CH + o] = acc[mt][p][r] + bov;
            }
    }
}

extern "C" void kernel_launch(void* const* d_in, const int* in_sizes, int n_in,
                              void* d_out, int out_size, void* d_ws, size_t ws_size,
                              hipStream_t stream) {
    const float* x2d = (const float*)d_in[0];
    const float* nw  = (const float*)d_in[1];
    const float* nb  = (const float*)d_in[2];
    const float* wq  = (const float*)d_in[3];
    const float* wk  = (const float*)d_in[4];
    const float* wv  = (const float*)d_in[5];
    const float* wb  = (const float*)d_in[6];
    const float* wg  = (const float*)d_in[7];
    const float* bg  = (const float*)d_in[8];
    const float* wo  = (const float*)d_in[9];
    const float* bo  = (const float*)d_in[10];
    float* out = (float*)d_out;

    float* bias = (float*)d_ws;
    bf16*  q    = (bf16*)((float*)d_ws + (size_t)NH * NPX);
    bf16*  k    = q + (size_t)NPX * CH;
    bf16*  v    = k + (size_t)NPX * CH;
    bf16*  g    = v + (size_t)NPX * CH;
    bf16*  wgt  = g + (size_t)NPX * CH;
    bf16*  wob  = wgt + 4 * 16384;

    prep_kernel<<<80, 256, 0, stream>>>(wq, wk, wv, wg, wo, wgt);
    proj_kernel<<<NPX / BPX, 256, 0, stream>>>(x2d, nw, nb, wgt, bg, wb, q, k, v, g, bias);
    attn_kernel<<<dim3(NRES, NH), 256, 0, stream>>>(q, k, v, bias, g, q);
    out_kernel<<<NPX / BPX, 256, 0, stream>>>(q, wob, bo, out);
}

// Round 8
// 117.522 us; speedup vs baseline: 4.6407x; 1.0081x over previous
//
#include <hip/hip_runtime.h>
#include <hip/hip_bf16.h>

#define NRES 256
#define CH   128
#define NH   4
#define HD   32
#define NPX  (NRES*NRES)   // 65536 pixels
#define BPX  64            // pixels per block in GEMM kernels
#define LOG2E 1.4426950408889634f

typedef __hip_bfloat16 bf16;
typedef __attribute__((ext_vector_type(8))) short bf16x8;
typedef __attribute__((ext_vector_type(4))) float f32x4;
typedef __attribute__((ext_vector_type(16))) float f32x16;
typedef __attribute__((ext_vector_type(2))) unsigned int uint2v;

__device__ __forceinline__ float lo_f(unsigned u) { return __uint_as_float(u << 16); }
__device__ __forceinline__ float hi_f(unsigned u) { return __uint_as_float(u & 0xffff0000u); }
__device__ __forceinline__ float fexp2(float x) { return __builtin_amdgcn_exp2f(x); }
__device__ __forceinline__ unsigned pk2(float a, float b) {
    unsigned short ua = __bfloat16_as_ushort(__float2bfloat16(a));
    unsigned short ub = __bfloat16_as_ushort(__float2bfloat16(b));
    return (unsigned)ua | ((unsigned)ub << 16);
}

// ---------------- Kernel 0: convert weights f32 -> bf16 ----------------
__global__ __launch_bounds__(256) void prep_kernel(const float* __restrict__ wq,
                                                   const float* __restrict__ wk,
                                                   const float* __restrict__ wv,
                                                   const float* __restrict__ wg,
                                                   const float* __restrict__ wo,
                                                   bf16* __restrict__ dst) {
    int mat = blockIdx.x >> 4;
    int off = ((blockIdx.x & 15) * 256 + threadIdx.x) * 4;
    const float* srcs[5] = {wq, wk, wv, wg, wo};
    float4 v4 = *reinterpret_cast<const float4*>(srcs[mat] + off);
    uint2 o;
    o.x = pk2(v4.x, v4.y);
    o.y = pk2(v4.z, v4.w);
    *reinterpret_cast<uint2*>(dst + (size_t)mat * 16384 + off) = o;
}

// ---------------- Kernel 1: LN + MFMA projections q,k,v,g + pair bias ----------------
__global__ __launch_bounds__(256) void proj_kernel(const float* __restrict__ x2d,
                                                   const float* __restrict__ nw,
                                                   const float* __restrict__ nb,
                                                   const bf16* __restrict__ wgt,
                                                   const float* __restrict__ bg,
                                                   const float* __restrict__ wb,
                                                   bf16* __restrict__ q,
                                                   bf16* __restrict__ k,
                                                   bf16* __restrict__ v,
                                                   bf16* __restrict__ g,
                                                   float* __restrict__ bias) {
    __shared__ float xs32[BPX][132];
    __shared__ short xsb[BPX][128];
    __shared__ float nwl[128], nbl[128];

    int t = threadIdx.x;
    size_t pbase = (size_t)blockIdx.x * BPX;

    if (t < 32) {
        *reinterpret_cast<float4*>(&nwl[t * 4]) = *reinterpret_cast<const float4*>(nw + t * 4);
        *reinterpret_cast<float4*>(&nbl[t * 4]) = *reinterpret_cast<const float4*>(nb + t * 4);
    }
    for (int it = 0; it < 8; ++it) {
        int idx = (it * 256 + t) * 4;
        int px = idx >> 7, c = idx & 127;
        *reinterpret_cast<float4*>(&xs32[px][c]) =
            *reinterpret_cast<const float4*>(x2d + pbase * CH + idx);
    }
    __syncthreads();

    {
        int px = t >> 2, lo = t & 3;
        float vals[32];
        float s = 0.f, ss = 0.f;
        #pragma unroll
        for (int cc = 0; cc < 32; ++cc) {
            float x = xs32[px][lo + 4 * cc];
            vals[cc] = x; s += x; ss += x * x;
        }
        s += __shfl_xor(s, 1); ss += __shfl_xor(ss, 1);
        s += __shfl_xor(s, 2); ss += __shfl_xor(ss, 2);
        float mu  = s * (1.0f / CH);
        float var = ss * (1.0f / CH) - mu * mu;
        float rs  = rsqrtf(var + 1e-5f);
        #pragma unroll
        for (int cc = 0; cc < 32; ++cc) {
            int c = lo + 4 * cc;
            float xv = (vals[cc] - mu) * rs * nwl[c] + nbl[c];
            xs32[px][c] = xv;
            int sc = ((((c >> 3) ^ px) & 7) << 3) | (c & 7) | (c & 64);
            xsb[px][sc] = (short)__bfloat16_as_ushort(__float2bfloat16(xv));
        }
    }
    __syncthreads();

    int w  = t >> 6, l = t & 63;
    int ll = l & 15, lg = l >> 4;
    bf16* Os[4] = {q, k, v, g};
    const float qscale = 0.17677669529663689f * LOG2E;   // 1/sqrt(32) * log2(e)

    #pragma unroll
    for (int mat = 0; mat < 4; ++mat) {
        const bf16* W = wgt + (size_t)mat * 16384;
        bf16x8 bfr[2][4];
        #pragma unroll
        for (int p = 0; p < 2; ++p)
            #pragma unroll
            for (int kt = 0; kt < 4; ++kt)
                bfr[p][kt] = *reinterpret_cast<const bf16x8*>(
                    W + (size_t)((2 * w + p) * 16 + ll) * CH + kt * 32 + lg * 8);

        f32x4 acc[4][2];
        #pragma unroll
        for (int mt = 0; mt < 4; ++mt)
            #pragma unroll
            for (int p = 0; p < 2; ++p) acc[mt][p] = (f32x4){0.f, 0.f, 0.f, 0.f};

        #pragma unroll
        for (int kt = 0; kt < 4; ++kt) {
            bf16x8 a[4];
            #pragma unroll
            for (int mt = 0; mt < 4; ++mt) {
                int row = 16 * mt + ll;
                int gr  = (kt * 4 + lg) ^ (row & 7);
                a[mt] = *reinterpret_cast<const bf16x8*>(&xsb[row][gr * 8]);
            }
            #pragma unroll
            for (int mt = 0; mt < 4; ++mt)
                #pragma unroll
                for (int p = 0; p < 2; ++p)
                    acc[mt][p] = __builtin_amdgcn_mfma_f32_16x16x32_bf16(a[mt], bfr[p][kt], acc[mt][p], 0, 0, 0);
        }

        #pragma unroll
        for (int p = 0; p < 2; ++p) {
            int o = (2 * w + p) * 16 + ll;
            float bgv = (mat == 3) ? bg[o] : 0.f;
            #pragma unroll
            for (int mt = 0; mt < 4; ++mt) {
                #pragma unroll
                for (int r = 0; r < 4; ++r) {
                    int prow = 16 * mt + lg * 4 + r;
                    float valf = acc[mt][p][r];
                    if (mat == 0) valf *= qscale;
                    if (mat == 3) valf = 1.f / (1.f + __expf(-(valf + bgv)));
                    Os[mat][(pbase + prow) * CH + o] = __float2bfloat16(valf);
                }
            }
        }
    }

    {
        int px = t >> 2, h = t & 3;
        float a = 0.f;
        for (int c = 0; c < CH; ++c) a += xs32[px][c] * wb[h * CH + c];
        bias[(size_t)h * NPX + pbase + px] = a * LOG2E;
    }
}

// ---------------- Kernel 2: MFMA flash attention per (m,h), 32x32 shape ----------------
// 4 waves x 64 q-rows (2 i-groups of 32); j in 32-wide tiles; P via permlane32_swap
__global__ __launch_bounds__(256, 4) void attn_kernel(const bf16* q,
                                                      const bf16* __restrict__ kk,
                                                      const bf16* __restrict__ vv,
                                                      const float* __restrict__ bias,
                                                      const bf16* __restrict__ gg,
                                                      bf16* attn) {
    __shared__ short vt[HD][NRES];     // 16 KB, transposed V, granule-XOR swizzled

    int t   = threadIdx.x;
    int w   = t >> 6;
    int l   = t & 63;
    int l31 = l & 31;
    int hi5 = l >> 5;
    int m = blockIdx.x, h = blockIdx.y;
    size_t base = ((size_t)m * NRES) * CH + (size_t)h * HD;

    // stage V transposed + swizzled
    for (int it = 0; it < 4; ++it) {
        int e8 = t + 256 * it;
        int j  = e8 >> 2;
        int d0 = (e8 & 3) * 8;
        uint4 vu = *reinterpret_cast<const uint4*>(vv + base + (size_t)j * CH + d0);
        union { uint4 u; short s[8]; } vc; vc.u = vu;
        #pragma unroll
        for (int s = 0; s < 8; ++s)
            vt[d0 + s][j ^ (8 * s)] = vc.s[s];
    }

    // Q fragments (B-operand, 32x32x16): col i = w*64+ig*32+l31, k = d = 16*tt + 8*hi5 + e
    bf16x8 qf[2][2];
    #pragma unroll
    for (int ig = 0; ig < 2; ++ig)
        #pragma unroll
        for (int tt = 0; tt < 2; ++tt)
            qf[ig][tt] = *reinterpret_cast<const bf16x8*>(
                q + base + (size_t)(w * 64 + ig * 32 + l31) * CH + tt * 16 + hi5 * 8);

    __syncthreads();

    float m_run[2] = {-1e30f, -1e30f};
    float l_run[2] = {0.f, 0.f};
    f32x16 oacc[2];
    #pragma unroll
    for (int ig = 0; ig < 2; ++ig)
        #pragma unroll
        for (int r = 0; r < 16; ++r) oacc[ig][r] = 0.f;

    const float* bh = bias + (size_t)h * NPX;

    for (int jt = 0; jt < 8; ++jt) {
        int j0 = jt * 32;

        // K fragments (A-operand): row j = j0 + l31, k = d
        bf16x8 kf0 = *reinterpret_cast<const bf16x8*>(kk + base + (size_t)(j0 + l31) * CH + hi5 * 8);
        bf16x8 kf1 = *reinterpret_cast<const bf16x8*>(kk + base + (size_t)(j0 + l31) * CH + 16 + hi5 * 8);

        // S^T tile: C col i = l31 (+32ig), row j_local = (r&3)+8*(r>>2)+4*hi5
        f32x16 sac[2];
        #pragma unroll
        for (int ig = 0; ig < 2; ++ig) {
            f32x16 zz;
            #pragma unroll
            for (int r = 0; r < 16; ++r) zz[r] = 0.f;
            zz = __builtin_amdgcn_mfma_f32_32x32x16_bf16(kf0, qf[ig][0], zz, 0, 0, 0);
            sac[ig] = __builtin_amdgcn_mfma_f32_32x32x16_bf16(kf1, qf[ig][1], zz, 0, 0, 0);
        }

        __builtin_amdgcn_s_setprio(1);
        // bias add (exp2 domain)
        #pragma unroll
        for (int ig = 0; ig < 2; ++ig) {
            int i = w * 64 + ig * 32 + l31;
            #pragma unroll
            for (int rq = 0; rq < 4; ++rq) {
                float4 b4 = *reinterpret_cast<const float4*>(bh + (size_t)i * NRES + j0 + 8 * rq + 4 * hi5);
                sac[ig][4 * rq + 0] += b4.x; sac[ig][4 * rq + 1] += b4.y;
                sac[ig][4 * rq + 2] += b4.z; sac[ig][4 * rq + 3] += b4.w;
            }
        }
        __builtin_amdgcn_s_setprio(0);

        // online softmax per i-group: one shfl per reduce (lanes l, l+32 share i)
        #pragma unroll
        for (int ig = 0; ig < 2; ++ig) {
            float a0 = fmaxf(sac[ig][0], sac[ig][1]),  a1 = fmaxf(sac[ig][2], sac[ig][3]);
            float a2 = fmaxf(sac[ig][4], sac[ig][5]),  a3 = fmaxf(sac[ig][6], sac[ig][7]);
            float a4 = fmaxf(sac[ig][8], sac[ig][9]),  a5 = fmaxf(sac[ig][10], sac[ig][11]);
            float a6 = fmaxf(sac[ig][12], sac[ig][13]), a7 = fmaxf(sac[ig][14], sac[ig][15]);
            float mx = fmaxf(fmaxf(fmaxf(a0, a1), fmaxf(a2, a3)), fmaxf(fmaxf(a4, a5), fmaxf(a6, a7)));
            mx = fmaxf(mx, __shfl_xor(mx, 32));

            // defer-max: skip rescale when growth small (p bounded by 2^8)
            if (!__all(mx <= m_run[ig] + 8.f)) {
                float mnew = fmaxf(m_run[ig], mx);
                float sc = fexp2(m_run[ig] - mnew);
                l_run[ig] *= sc;
                #pragma unroll
                for (int r = 0; r < 16; ++r) oacc[ig][r] *= sc;
                m_run[ig] = mnew;
            }
            float mm = m_run[ig];
            #pragma unroll
            for (int r = 0; r < 16; ++r) sac[ig][r] = fexp2(sac[ig][r] - mm);
            float s0 = sac[ig][0] + sac[ig][1],  s1 = sac[ig][2] + sac[ig][3];
            float s2 = sac[ig][4] + sac[ig][5],  s3 = sac[ig][6] + sac[ig][7];
            float s4 = sac[ig][8] + sac[ig][9],  s5 = sac[ig][10] + sac[ig][11];
            float s6 = sac[ig][12] + sac[ig][13], s7 = sac[ig][14] + sac[ig][15];
            float psum = ((s0 + s1) + (s2 + s3)) + ((s4 + s5) + (s6 + s7));
            psum += __shfl_xor(psum, 32);
            l_run[ig] += psum;
        }

        // PV: O^T += V^T * P^T; P B-frag built in-register via permlane32_swap
        // swap(first,second): first[hi lanes] <-> second[lo lanes]
        // args (x=low-j word, y=mid-j word) -> r[0] = {x.lo|y.lo} = B-word k(0,1),
        //                                      r[1] = {x.hi|y.hi} = B-word k(4,5)
        #pragma unroll
        for (int tt = 0; tt < 2; ++tt) {
            bf16x8 vf = *reinterpret_cast<const bf16x8*>(
                &vt[l31][(j0 + 16 * tt + 8 * hi5) ^ (8 * (l31 & 7))]);
            #pragma unroll
            for (int ig = 0; ig < 2; ++ig) {
                unsigned x0 = pk2(sac[ig][8 * tt + 0], sac[ig][8 * tt + 1]);
                unsigned x1 = pk2(sac[ig][8 * tt + 2], sac[ig][8 * tt + 3]);
                unsigned y0 = pk2(sac[ig][8 * tt + 4], sac[ig][8 * tt + 5]);
                unsigned y1 = pk2(sac[ig][8 * tt + 6], sac[ig][8 * tt + 7]);
                uint2v r0 = __builtin_amdgcn_permlane32_swap(x0, y0, false, false);
                uint2v r1 = __builtin_amdgcn_permlane32_swap(x1, y1, false, false);
                union { unsigned u[4]; bf16x8 v; } pf;
                pf.u[0] = r0[0];  // k 0,1
                pf.u[1] = r1[0];  // k 2,3
                pf.u[2] = r0[1];  // k 4,5
                pf.u[3] = r1[1];  // k 6,7
                oacc[ig] = __builtin_amdgcn_mfma_f32_32x32x16_bf16(vf, pf.v, oacc[ig], 0, 0, 0);
            }
        }
    }

    // epilogue: normalize, gate, store; C col i = l31(+32ig), row d = (r&3)+8*(r>>2)+4*hi5
    #pragma unroll
    for (int ig = 0; ig < 2; ++ig) {
        float inv = 1.f / l_run[ig];
        size_t prow = base + (size_t)(w * 64 + ig * 32 + l31) * CH;
        #pragma unroll
        for (int rq = 0; rq < 4; ++rq) {
            int d0 = 8 * rq + 4 * hi5;
            uint2 gu = *reinterpret_cast<const uint2*>(gg + prow + d0);
            float g0 = lo_f(gu.x), g1 = hi_f(gu.x), g2 = lo_f(gu.y), g3 = hi_f(gu.y);
            uint2 ow;
            ow.x = pk2(oacc[ig][4 * rq + 0] * inv * g0, oacc[ig][4 * rq + 1] * inv * g1);
            ow.y = pk2(oacc[ig][4 * rq + 2] * inv * g2, oacc[ig][4 * rq + 3] * inv * g3);
            *reinterpret_cast<uint2*>(attn + prow + d0) = ow;
        }
    }
}

// ---------------- Kernel 3: MFMA output projection (f32 out) ----------------
__global__ __launch_bounds__(256) void out_kernel(const bf16* __restrict__ ga,
                                                  const bf16* __restrict__ wob,
                                                  const float* __restrict__ bo,
                                                  float* __restrict__ out) {
    __shared__ short xsb[BPX][128];
    int t = threadIdx.x;
    size_t pbase = (size_t)blockIdx.x * BPX;

    for (int it = 0; it < 4; ++it) {
        int idx = (it * 256 + t) * 8;
        int px = idx >> 7, c = idx & 127;
        int gr = c >> 3;
        uint4 u = *reinterpret_cast<const uint4*>(ga + pbase * CH + idx);
        *reinterpret_cast<uint4*>(&xsb[px][(gr ^ (px & 7)) * 8]) = u;
    }
    __syncthreads();

    int w  = t >> 6, l = t & 63;
    int ll = l & 15, lg = l >> 4;

    bf16x8 bfr[2][4];
    #pragma unroll
    for (int p = 0; p < 2; ++p)
        #pragma unroll
        for (int kt = 0; kt < 4; ++kt)
            bfr[p][kt] = *reinterpret_cast<const bf16x8*>(
                wob + (size_t)((2 * w + p) * 16 + ll) * CH + kt * 32 + lg * 8);

    f32x4 acc[4][2];
    #pragma unroll
    for (int mt = 0; mt < 4; ++mt)
        #pragma unroll
        for (int p = 0; p < 2; ++p) acc[mt][p] = (f32x4){0.f, 0.f, 0.f, 0.f};

    #pragma unroll
    for (int kt = 0; kt < 4; ++kt) {
        bf16x8 a[4];
        #pragma unroll
        for (int mt = 0; mt < 4; ++mt) {
            int row = 16 * mt + ll;
            int gr  = (kt * 4 + lg) ^ (row & 7);
            a[mt] = *reinterpret_cast<const bf16x8*>(&xsb[row][gr * 8]);
        }
        #pragma unroll
        for (int mt = 0; mt < 4; ++mt)
            #pragma unroll
            for (int p = 0; p < 2; ++p)
                acc[mt][p] = __builtin_amdgcn_mfma_f32_16x16x32_bf16(a[mt], bfr[p][kt], acc[mt][p], 0, 0, 0);
    }

    #pragma unroll
    for (int p = 0; p < 2; ++p) {
        int o = (2 * w + p) * 16 + ll;
        float bov = bo[o];
        #pragma unroll
        for (int mt = 0; mt < 4; ++mt)
            #pragma unroll
            for (int r = 0; r < 4; ++r) {
                int prow = 16 * mt + lg * 4 + r;
                out[(pbase + prow) * CH + o] = acc[mt][p][r] + bov;
            }
    }
}

extern "C" void kernel_launch(void* const* d_in, const int* in_sizes, int n_in,
                              void* d_out, int out_size, void* d_ws, size_t ws_size,
                              hipStream_t stream) {
    const float* x2d = (const float*)d_in[0];
    const float* nw  = (const float*)d_in[1];
    const float* nb  = (const float*)d_in[2];
    const float* wq  = (const float*)d_in[3];
    const float* wk  = (const float*)d_in[4];
    const float* wv  = (const float*)d_in[5];
    const float* wb  = (const float*)d_in[6];
    const float* wg  = (const float*)d_in[7];
    const float* bg  = (const float*)d_in[8];
    const float* wo  = (const float*)d_in[9];
    const float* bo  = (const float*)d_in[10];
    float* out = (float*)d_out;

    float* bias = (float*)d_ws;
    bf16*  q    = (bf16*)((float*)d_ws + (size_t)NH * NPX);
    bf16*  k    = q + (size_t)NPX * CH;
    bf16*  v    = k + (size_t)NPX * CH;
    bf16*  g    = v + (size_t)NPX * CH;
    bf16*  wgt  = g + (size_t)NPX * CH;
    bf16*  wob  = wgt + 4 * 16384;

    prep_kernel<<<80, 256, 0, stream>>>(wq, wk, wv, wg, wo, wgt);
    proj_kernel<<<NPX / BPX, 256, 0, stream>>>(x2d, nw, nb, wgt, bg, wb, q, k, v, g, bias);
    attn_kernel<<<dim3(NRES, NH), 256, 0, stream>>>(q, k, v, bias, g, q);
    out_kernel<<<NPX / BPX, 256, 0, stream>>>(q, wob, bo, out);
}